// Round 8
// baseline (279.237 us; speedup 1.0000x reference)
//
#include <hip/hip_runtime.h>
#include <hip/hip_bf16.h>
#include <cfloat>

#define HD 128

typedef float f32x4 __attribute__((ext_vector_type(4)));
typedef __bf16 bf16x8 __attribute__((ext_vector_type(8)));

// -------- Kernel 1: segment bounds (batch is sorted) + work-queue reset ----
__global__ void seg_bounds_kernel(const int* __restrict__ batch, int n, int nseg,
                                  int* __restrict__ seg_start, int* __restrict__ ctr) {
  int b = blockIdx.x * blockDim.x + threadIdx.x;
  if (b == 0) *ctr = 0;            // reset dynamic queue every launch
  if (b > nseg) return;
  if (b == nseg) { seg_start[b] = n; return; }
  int lo = 0, hi = n;
  while (lo < hi) {
    int mid = (lo + hi) >> 1;
    if (batch[mid] < b) lo = mid + 1; else hi = mid;
  }
  seg_start[b] = lo;
}

// -------- Kernel 2: FUSED gate-score + online softmax + pooling ------------
// One wave per segment (atomic queue). REGISTER-DIET version:
//  pass 1 (score): h streamed through a 16-float rolling window -> bf16 cvt
//                  -> 32 MFMA; no 32-float tile buffer held.
//  pass 2 (pool):  re-read the same 8 float4 from L2 (guaranteed resident),
//                  fp32 fma into acc / fmax into gm.
// Target: <=170 total regs -> 3 waves/SIMD (12 waves/CU) for latency hiding.
// Score algebra: score = sumW2 - 2*sum(w2/(1+e^{2x})) (b2 cancels in softmax).
__global__ __launch_bounds__(256, 3) void fused_pool_kernel(
    const float* __restrict__ h, const float* __restrict__ w1,
    const float* __restrict__ b1, const float* __restrict__ w2,
    const int* __restrict__ seg_start, float* __restrict__ g, int B,
    int* __restrict__ ctr)
{
  __shared__ __bf16 sWt[HD * HD];  // W1^T bf16, XOR-swizzled 16B slots (32 KB)

  for (int i = threadIdx.x; i < HD * HD / 4; i += 256) {
    const int k = i >> 5;
    const int c4 = (i & 31) << 2;
    const float4 v = reinterpret_cast<const float4*>(w1)[i];
    const float vv[4] = {v.x, v.y, v.z, v.w};
#pragma unroll
    for (int q = 0; q < 4; ++q) {
      const int c = c4 + q;
      sWt[c * HD + ((((k >> 3) ^ (c & 15)) << 3) | (k & 7))] = (__bf16)vv[q];
    }
  }
  __syncthreads();

  const float LOG2E  = 1.44269504088896341f;
  const float LOG2E2 = 2.88539008177792681f;

  const int lane = threadIdx.x & 63;
  const int lr   = lane & 15;
  const int kl   = lane >> 4;

  float w2r[8], b1s[8];
#pragma unroll
  for (int f = 0; f < 8; ++f) {
    w2r[f] = w2[16 * f + lr];
    b1s[f] = LOG2E2 * b1[16 * f + lr];
  }
  float sumW2 = 0.f;
#pragma unroll
  for (int f = 0; f < 8; ++f) sumW2 += w2r[f];
  sumW2 += __shfl_xor(sumW2, 1, 16);
  sumW2 += __shfl_xor(sumW2, 2, 16);
  sumW2 += __shfl_xor(sumW2, 4, 16);
  sumW2 += __shfl_xor(sumW2, 8, 16);

  // B-fragment LDS byte offsets: addr(kt,f) = Cb + ((kt^hi2)<<6) + f*4096
  // (c & 15 == lr for every fragment column c = 16f + lr.)
  const int hi2 = (lr >> 2) & 3;
  int Cb = lr * 256 + ((kl ^ (lr & 3)) << 4);

  for (;;) {
    int b;
    if (lane == 0) b = atomicAdd(ctr, 1);
    b = __shfl(b, 0, 64);
    if (b >= B) break;

    const int s0  = seg_start[b];
    const int len = seg_start[b + 1] - s0;
    const int lenm1 = len - 1;
    const int nt  = (len + 15) >> 4;

    float m = -FLT_MAX, s = 0.f;
    float acc[32], gm[32];
#pragma unroll
    for (int j = 0; j < 32; ++j) { acc[j] = 0.f; gm[j] = -FLT_MAX; }

    for (int t = 0; t < nt; ++t) {
      const int nIt = t * 16 + lr;
      const bool valid = nIt < len;
      const float* rowp = h + (size_t)(s0 + min(nIt, lenm1)) * HD + 8 * kl;

      // opaque per-tile: keep the 32 B-frag LDS reads inside the loop
      asm volatile("" : "+v"(Cb));

      // ---- pass 1: score (rolling 16-float window) ----
      f32x4 macc[8];
#pragma unroll
      for (int f = 0; f < 8; ++f) macc[f] = (f32x4){0.f, 0.f, 0.f, 0.f};
      float4 c0 = *reinterpret_cast<const float4*>(rowp);
      float4 c1 = *reinterpret_cast<const float4*>(rowp + 4);
#pragma unroll
      for (int kt = 0; kt < 4; ++kt) {
        float4 n0, n1;
        if (kt < 3) {
          n0 = *reinterpret_cast<const float4*>(rowp + 32 * (kt + 1));
          n1 = *reinterpret_cast<const float4*>(rowp + 32 * (kt + 1) + 4);
        }
        bf16x8 acur;
        const float* pc0 = reinterpret_cast<const float*>(&c0);
        const float* pc1 = reinterpret_cast<const float*>(&c1);
#pragma unroll
        for (int j = 0; j < 4; ++j) {
          acur[j]     = (__bf16)pc0[j];
          acur[4 + j] = (__bf16)pc1[j];
        }
        const char* bp = reinterpret_cast<const char*>(sWt) +
                         (Cb + ((kt ^ hi2) << 6));
#pragma unroll
        for (int f = 0; f < 8; ++f) {
          const bf16x8 bfr = *reinterpret_cast<const bf16x8*>(bp + f * 4096);
          macc[f] = __builtin_amdgcn_mfma_f32_16x16x32_bf16(acur, bfr, macc[f],
                                                            0, 0, 0);
        }
        c0 = n0; c1 = n1;
      }

      // ---- epilogue: score -> online softmax weight ----
      float p2[4] = {0.f, 0.f, 0.f, 0.f};
#pragma unroll
      for (int f = 0; f < 8; ++f) {
#pragma unroll
        for (int r = 0; r < 4; ++r) {
          const float xe = fmaf(LOG2E2, macc[f][r], b1s[f]);
          const float e  = exp2f(xe);
          const float tt = __builtin_amdgcn_rcpf(1.f + e);
          p2[r] = fmaf(tt, w2r[f], p2[r]);
        }
      }
#pragma unroll
      for (int r = 0; r < 4; ++r) {
        p2[r] += __shfl_xor(p2[r], 1, 16);
        p2[r] += __shfl_xor(p2[r], 2, 16);
        p2[r] += __shfl_xor(p2[r], 4, 16);
        p2[r] += __shfl_xor(p2[r], 8, 16);
      }
      const float minp = fminf(fminf(p2[0], p2[1]), fminf(p2[2], p2[3]));
      float tmax = fmaf(-2.f, minp, sumW2);
      tmax = fmaxf(tmax, __shfl_xor(tmax, 16, 64));
      tmax = fmaxf(tmax, __shfl_xor(tmax, 32, 64));
      const int rr = lr & 3;
      const float psel = rr == 0 ? p2[0]
                       : (rr == 1 ? p2[1] : (rr == 2 ? p2[2] : p2[3]));
      const float vsc = fmaf(-2.f, psel, sumW2);
      const float sc  = __shfl(vsc, ((lr >> 2) << 4) | (lr & 3), 64);
      if (tmax > m) {                       // wave-uniform branch
        const float scl = exp2f((m - tmax) * LOG2E);
        s *= scl;
#pragma unroll
        for (int j = 0; j < 32; ++j) acc[j] *= scl;
        m = tmax;
      }
      const float w_ = valid ? exp2f((sc - m) * LOG2E) : 0.f;
      s += w_;

      // ---- pass 2: pooling re-read (L2-resident; pinned after w_) ----
      int dz = 0;
      asm volatile("" : "+v"(dz) : "v"(w_));   // order + anti-CSE
      const float* rowq = rowp + dz;
      float4 q0 = *reinterpret_cast<const float4*>(rowq);
      float4 q1 = *reinterpret_cast<const float4*>(rowq + 4);
#pragma unroll
      for (int kt = 0; kt < 4; ++kt) {
        float4 r0, r1;
        if (kt < 3) {
          r0 = *reinterpret_cast<const float4*>(rowq + 32 * (kt + 1));
          r1 = *reinterpret_cast<const float4*>(rowq + 32 * (kt + 1) + 4);
        }
        const float* pq0 = reinterpret_cast<const float*>(&q0);
        const float* pq1 = reinterpret_cast<const float*>(&q1);
#pragma unroll
        for (int j = 0; j < 4; ++j) {
          acc[8 * kt + j]     = fmaf(pq0[j], w_, acc[8 * kt + j]);
          gm[8 * kt + j]      = fmaxf(gm[8 * kt + j], pq0[j]);
          acc[8 * kt + 4 + j] = fmaf(pq1[j], w_, acc[8 * kt + 4 + j]);
          gm[8 * kt + 4 + j]  = fmaxf(gm[8 * kt + 4 + j], pq1[j]);
        }
        q0 = r0; q1 = r1;
      }
    }

    // reduce partials across the 16 lr lanes (features depend only on kl)
#pragma unroll
    for (int off = 1; off <= 8; off <<= 1) {
      s += __shfl_xor(s, off, 16);
#pragma unroll
      for (int j = 0; j < 32; ++j) {
        acc[j] += __shfl_xor(acc[j], off, 16);
        gm[j] = fmaxf(gm[j], __shfl_xor(gm[j], off, 16));
      }
    }

    if (lr == 0) {  // lanes 0,16,32,48: one per kl group
      const float invS = (s > 0.f) ? 1.f / s : 0.f;
#pragma unroll
      for (int kt = 0; kt < 4; ++kt) {
        const int fb = 32 * kt + 8 * kl;
        float4 va, vb, ma, mb;
        va.x = acc[8*kt+0]*invS; va.y = acc[8*kt+1]*invS;
        va.z = acc[8*kt+2]*invS; va.w = acc[8*kt+3]*invS;
        vb.x = acc[8*kt+4]*invS; vb.y = acc[8*kt+5]*invS;
        vb.z = acc[8*kt+6]*invS; vb.w = acc[8*kt+7]*invS;
        ma.x = gm[8*kt+0]; ma.y = gm[8*kt+1]; ma.z = gm[8*kt+2]; ma.w = gm[8*kt+3];
        mb.x = gm[8*kt+4]; mb.y = gm[8*kt+5]; mb.z = gm[8*kt+6]; mb.w = gm[8*kt+7];
        *reinterpret_cast<float4*>(&g[(size_t)b * 256 + fb])           = va;
        *reinterpret_cast<float4*>(&g[(size_t)b * 256 + fb + 4])       = vb;
        *reinterpret_cast<float4*>(&g[(size_t)b * 256 + 128 + fb])     = ma;
        *reinterpret_cast<float4*>(&g[(size_t)b * 256 + 128 + fb + 4]) = mb;
      }
    }
  }
}

// -------- Kernel 3: MLP head, 4 segments per block --------
__global__ __launch_bounds__(512) void mlp_kernel(
    const float* __restrict__ g, const float* __restrict__ w1,
    const float* __restrict__ b1, const float* __restrict__ w2,
    const float* __restrict__ b2, float* __restrict__ out)
{
  __shared__ float sg[4][256];
  __shared__ float sred[4][2];
  const int t = threadIdx.x;
  const int sidx = t >> 7;
  const int u = t & 127;
  const int b0 = blockIdx.x * 4;
  sg[sidx][u]       = g[(size_t)(b0 + sidx) * 256 + u];
  sg[sidx][u + 128] = g[(size_t)(b0 + sidx) * 256 + 128 + u];
  __syncthreads();
  float acc = b1[u];
#pragma unroll 8
  for (int k = 0; k < 256; ++k)
    acc = fmaf(sg[sidx][k], w1[k * HD + u], acc);
  float v = fmaxf(acc, 0.f) * w2[u];
#pragma unroll
  for (int off = 32; off >= 1; off >>= 1) v += __shfl_xor(v, off, 64);
  if ((t & 63) == 0) sred[sidx][(t >> 6) & 1] = v;
  __syncthreads();
  if (u == 0) out[b0 + sidx] = sred[sidx][0] + sred[sidx][1] + b2[0];
}

extern "C" void kernel_launch(void* const* d_in, const int* in_sizes, int n_in,
                              void* d_out, int out_size, void* d_ws, size_t ws_size,
                              hipStream_t stream) {
  const float* h       = (const float*)d_in[0];
  const int*   batch   = (const int*)d_in[1];
  const float* gate_w1 = (const float*)d_in[2];
  const float* gate_b1 = (const float*)d_in[3];
  const float* gate_w2 = (const float*)d_in[4];
  const float* mlp_w1  = (const float*)d_in[6];
  const float* mlp_b1  = (const float*)d_in[7];
  const float* mlp_w2  = (const float*)d_in[8];
  const float* mlp_b2  = (const float*)d_in[9];
  float* out = (float*)d_out;

  const int N = in_sizes[0] / HD;   // 1048576
  const int B = out_size;           // 4096

  char* ws = (char*)d_ws;
  float* g   = (float*)ws;                              // B*256 floats
  int*   seg = (int*)(ws + (size_t)B * 256 * 4);        // B+1 ints
  int*   ctr = seg + (B + 2);                           // work-queue counter

  seg_bounds_kernel<<<(B + 256) / 256, 256, 0, stream>>>(batch, N, B, seg, ctr);
  // Persistent: 768 blocks (3/CU) x 4 waves = 3072 waves; segments claimed
  // dynamically from the queue.
  fused_pool_kernel<<<768, 256, 0, stream>>>(h, gate_w1, gate_b1, gate_w2,
                                             seg, g, B, ctr);
  mlp_kernel<<<B / 4, 512, 0, stream>>>(g, mlp_w1, mlp_b1, mlp_w2, mlp_b2, out);
}

// Round 9
// 185.359 us; speedup vs baseline: 1.5065x; 1.5065x over previous
//
#include <hip/hip_runtime.h>
#include <hip/hip_bf16.h>
#include <cfloat>

#define HD 128

typedef float f32x4 __attribute__((ext_vector_type(4)));
typedef __bf16 bf16x8 __attribute__((ext_vector_type(8)));

// -------- Kernel 1: segment bounds (batch is sorted) --------
__global__ void seg_bounds_kernel(const int* __restrict__ batch, int n, int nseg,
                                  int* __restrict__ seg_start) {
  int b = blockIdx.x * blockDim.x + threadIdx.x;
  if (b > nseg) return;
  if (b == nseg) { seg_start[b] = n; return; }
  int lo = 0, hi = n;
  while (lo < hi) {
    int mid = (lo + hi) >> 1;
    if (batch[mid] < b) lo = mid + 1; else hi = mid;
  }
  seg_start[b] = lo;
}

// -------- Kernel 2: FUSED gate-score + FIXED-SHIFT softmax + pooling -------
// One wave per segment (static, 4096 waves). Double-buffered h (hA/hB).
// Softmax needs NO running max: |score - const| = |2*sum(w2*sigma)| <=
// 2*sum|w2| (~11.3 worst case), so w = exp2(-2*log2e*psel) is always in
// fp32 range and ratios match the reference's shifted softmax exactly.
// Per kt-phase the 8 B-fragments are batch-read into bfr[8] BEFORE the 8
// MFMAs so the LDS latency (~120cy) is paid once per phase, not per MFMA.

#define LOAD_TILE(BUF, T)                                                   \
  {                                                                         \
    const int nIt_ = (T) * 16 + lr;                                         \
    const size_t row_ = (size_t)s0 + (size_t)min(nIt_, lenm1);              \
    const float* hp_ = h + row_ * HD + 8 * kl;                              \
    _Pragma("unroll")                                                       \
    for (int kt = 0; kt < 4; ++kt) {                                        \
      *reinterpret_cast<float4*>(&BUF[8 * kt]) =                            \
          *reinterpret_cast<const float4*>(hp_ + 32 * kt);                  \
      *reinterpret_cast<float4*>(&BUF[8 * kt + 4]) =                        \
          *reinterpret_cast<const float4*>(hp_ + 32 * kt + 4);              \
    }                                                                       \
  }

#define PROC_TILE(BUF, T)                                                   \
  {                                                                         \
    const bool valid_ = ((T) * 16 + lr) < len;                              \
    bf16x8 a_[4];                                                           \
    _Pragma("unroll")                                                       \
    for (int kt = 0; kt < 4; ++kt)                                          \
      _Pragma("unroll")                                                     \
      for (int j = 0; j < 8; ++j) a_[kt][j] = (__bf16)BUF[8 * kt + j];      \
    /* opaque: keep B-frag reads inside the loop (anti-LICM) */             \
    asm volatile("" : "+v"(Cb));                                            \
    f32x4 macc_[8];                                                         \
    _Pragma("unroll")                                                       \
    for (int f = 0; f < 8; ++f) macc_[f] = (f32x4){0.f, 0.f, 0.f, 0.f};     \
    _Pragma("unroll")                                                       \
    for (int kt = 0; kt < 4; ++kt) {                                        \
      const char* bp_ = reinterpret_cast<const char*>(sWt) +                \
                        (Cb + ((kt ^ hi2) << 6));                           \
      bf16x8 bfr_[8];                                                       \
      _Pragma("unroll")                                                     \
      for (int f = 0; f < 8; ++f)                                           \
        bfr_[f] = *reinterpret_cast<const bf16x8*>(bp_ + f * 4096);         \
      _Pragma("unroll")                                                     \
      for (int f = 0; f < 8; ++f)                                           \
        macc_[f] =                                                          \
            __builtin_amdgcn_mfma_f32_16x16x32_bf16(a_[kt], bfr_[f],        \
                                                    macc_[f], 0, 0, 0);     \
    }                                                                       \
    float p2_[4] = {0.f, 0.f, 0.f, 0.f};                                    \
    _Pragma("unroll")                                                       \
    for (int f = 0; f < 8; ++f) {                                           \
      _Pragma("unroll")                                                     \
      for (int r = 0; r < 4; ++r) {                                         \
        const float xe_ = fmaf(LOG2E2, macc_[f][r], b1s[f]);                \
        const float e_ = exp2f(xe_);                                        \
        const float t_ = __builtin_amdgcn_rcpf(1.f + e_);                   \
        p2_[r] = fmaf(t_, w2r[f], p2_[r]);                                  \
      }                                                                     \
    }                                                                       \
    _Pragma("unroll")                                                       \
    for (int r = 0; r < 4; ++r) {                                           \
      p2_[r] += __shfl_xor(p2_[r], 1, 16);                                  \
      p2_[r] += __shfl_xor(p2_[r], 2, 16);                                  \
      p2_[r] += __shfl_xor(p2_[r], 4, 16);                                  \
      p2_[r] += __shfl_xor(p2_[r], 8, 16);                                  \
    }                                                                       \
    const int rr_ = lr & 3;                                                 \
    const float psel_ =                                                     \
        rr_ == 0 ? p2_[0] : (rr_ == 1 ? p2_[1] : (rr_ == 2 ? p2_[2]         \
                                                            : p2_[3]));     \
    const float sc_ = __shfl(psel_, ((lr >> 2) << 4) | (lr & 3), 64);       \
    const float w_ = valid_ ? exp2f(sc_ * NEG2LOG2E) : 0.f;                 \
    s += w_;                                                                \
    _Pragma("unroll")                                                       \
    for (int j = 0; j < 32; ++j) {                                          \
      acc[j] = fmaf(BUF[j], w_, acc[j]);                                    \
      gm[j] = fmaxf(gm[j], BUF[j]);                                         \
    }                                                                       \
  }

__global__ __launch_bounds__(256, 2) void fused_pool_kernel(
    const float* __restrict__ h, const float* __restrict__ w1,
    const float* __restrict__ b1, const float* __restrict__ w2,
    const int* __restrict__ seg_start, float* __restrict__ g, int B)
{
  __shared__ __bf16 sWt[HD * HD];  // W1^T bf16, XOR-swizzled 16B slots (32 KB)

  for (int i = threadIdx.x; i < HD * HD / 4; i += 256) {
    const int k = i >> 5;
    const int c4 = (i & 31) << 2;
    const float4 v = reinterpret_cast<const float4*>(w1)[i];
    const float vv[4] = {v.x, v.y, v.z, v.w};
#pragma unroll
    for (int q = 0; q < 4; ++q) {
      const int c = c4 + q;
      sWt[c * HD + ((((k >> 3) ^ (c & 15)) << 3) | (k & 7))] = (__bf16)vv[q];
    }
  }
  __syncthreads();

  const float LOG2E2    = 2.88539008177792681f;   // 2*log2(e)
  const float NEG2LOG2E = -2.88539008177792681f;  // -2*log2(e)

  const int lane = threadIdx.x & 63;
  const int wid  = threadIdx.x >> 6;
  const int lr   = lane & 15;
  const int kl   = lane >> 4;

  float w2r[8], b1s[8];
#pragma unroll
  for (int f = 0; f < 8; ++f) {
    w2r[f] = w2[16 * f + lr];
    b1s[f] = LOG2E2 * b1[16 * f + lr];
  }

  // B-fragment LDS byte offsets: addr(kt,f) = Cb + ((kt^hi2)<<6) + f*4096
  // (c & 15 == lr for every fragment column c = 16f + lr.)
  const int hi2 = (lr >> 2) & 3;
  int Cb = lr * 256 + ((kl ^ (lr & 3)) << 4);

  const int segStride = gridDim.x * 4;
  for (int b = blockIdx.x * 4 + wid; b < B; b += segStride) {
    const int s0  = seg_start[b];
    const int len = seg_start[b + 1] - s0;
    const int lenm1 = len - 1;
    const int nt  = (len + 15) >> 4;

    float s = 0.f;
    float acc[32], gm[32];
#pragma unroll
    for (int j = 0; j < 32; ++j) { acc[j] = 0.f; gm[j] = -FLT_MAX; }

    if (nt > 0) {
      float hA[32], hB[32];
      LOAD_TILE(hA, 0)
      int t = 0;
      for (; t + 1 < nt; t += 2) {
        LOAD_TILE(hB, t + 1)
        PROC_TILE(hA, t)
        if (t + 2 < nt) LOAD_TILE(hA, t + 2)
        PROC_TILE(hB, t + 1)
      }
      if (t < nt) PROC_TILE(hA, t)
    }

    // reduce partials across the 16 lr lanes (features depend only on kl)
#pragma unroll
    for (int off = 1; off <= 8; off <<= 1) {
      s += __shfl_xor(s, off, 16);
#pragma unroll
      for (int j = 0; j < 32; ++j) {
        acc[j] += __shfl_xor(acc[j], off, 16);
        gm[j] = fmaxf(gm[j], __shfl_xor(gm[j], off, 16));
      }
    }

    if (lr == 0) {  // lanes 0,16,32,48: one per kl group
      const float invS = (s > 0.f) ? 1.f / s : 0.f;
#pragma unroll
      for (int kt = 0; kt < 4; ++kt) {
        const int fb = 32 * kt + 8 * kl;
        float4 va, vb, ma, mb;
        va.x = acc[8*kt+0]*invS; va.y = acc[8*kt+1]*invS;
        va.z = acc[8*kt+2]*invS; va.w = acc[8*kt+3]*invS;
        vb.x = acc[8*kt+4]*invS; vb.y = acc[8*kt+5]*invS;
        vb.z = acc[8*kt+6]*invS; vb.w = acc[8*kt+7]*invS;
        ma.x = gm[8*kt+0]; ma.y = gm[8*kt+1]; ma.z = gm[8*kt+2]; ma.w = gm[8*kt+3];
        mb.x = gm[8*kt+4]; mb.y = gm[8*kt+5]; mb.z = gm[8*kt+6]; mb.w = gm[8*kt+7];
        *reinterpret_cast<float4*>(&g[(size_t)b * 256 + fb])           = va;
        *reinterpret_cast<float4*>(&g[(size_t)b * 256 + fb + 4])       = vb;
        *reinterpret_cast<float4*>(&g[(size_t)b * 256 + 128 + fb])     = ma;
        *reinterpret_cast<float4*>(&g[(size_t)b * 256 + 128 + fb + 4]) = mb;
      }
    }
  }
}

// -------- Kernel 3: MLP head, 4 segments per block --------
__global__ __launch_bounds__(512) void mlp_kernel(
    const float* __restrict__ g, const float* __restrict__ w1,
    const float* __restrict__ b1, const float* __restrict__ w2,
    const float* __restrict__ b2, float* __restrict__ out)
{
  __shared__ float sg[4][256];
  __shared__ float sred[4][2];
  const int t = threadIdx.x;
  const int sidx = t >> 7;
  const int u = t & 127;
  const int b0 = blockIdx.x * 4;
  sg[sidx][u]       = g[(size_t)(b0 + sidx) * 256 + u];
  sg[sidx][u + 128] = g[(size_t)(b0 + sidx) * 256 + 128 + u];
  __syncthreads();
  float acc = b1[u];
#pragma unroll 8
  for (int k = 0; k < 256; ++k)
    acc = fmaf(sg[sidx][k], w1[k * HD + u], acc);
  float v = fmaxf(acc, 0.f) * w2[u];
#pragma unroll
  for (int off = 32; off >= 1; off >>= 1) v += __shfl_xor(v, off, 64);
  if ((t & 63) == 0) sred[sidx][(t >> 6) & 1] = v;
  __syncthreads();
  if (u == 0) out[b0 + sidx] = sred[sidx][0] + sred[sidx][1] + b2[0];
}

extern "C" void kernel_launch(void* const* d_in, const int* in_sizes, int n_in,
                              void* d_out, int out_size, void* d_ws, size_t ws_size,
                              hipStream_t stream) {
  const float* h       = (const float*)d_in[0];
  const int*   batch   = (const int*)d_in[1];
  const float* gate_w1 = (const float*)d_in[2];
  const float* gate_b1 = (const float*)d_in[3];
  const float* gate_w2 = (const float*)d_in[4];
  const float* mlp_w1  = (const float*)d_in[6];
  const float* mlp_b1  = (const float*)d_in[7];
  const float* mlp_w2  = (const float*)d_in[8];
  const float* mlp_b2  = (const float*)d_in[9];
  float* out = (float*)d_out;

  const int N = in_sizes[0] / HD;   // 1048576
  const int B = out_size;           // 4096

  char* ws = (char*)d_ws;
  float* g   = (float*)ws;                              // B*256 floats
  int*   seg = (int*)(ws + (size_t)B * 256 * 4);        // B+1 ints

  seg_bounds_kernel<<<(B + 256) / 256, 256, 0, stream>>>(batch, N, B, seg);
  // 1024 blocks x 4 waves = 4096 waves -> one segment per wave (static).
  fused_pool_kernel<<<1024, 256, 0, stream>>>(h, gate_w1, gate_b1, gate_w2,
                                              seg, g, B);
  mlp_kernel<<<B / 4, 512, 0, stream>>>(g, mlp_w1, mlp_b1, mlp_w2, mlp_b2, out);
}